// Round 1
// baseline (1087.883 us; speedup 1.0000x reference)
//
#include <hip/hip_runtime.h>
#include <math.h>

// Problem constants (from reference): B=8, N=2048, D=512, S=4096
#define BATCH 8
#define NNODES 2048
#define DDIM 512
#define SWAPS 4096
#define M_TOTAL (BATCH * SWAPS)   // 32768 rows
#define K1 (4 * DDIM)             // 2048
#define N1 DDIM                   // 512
#define K2 DDIM                   // 512
#define N2 (DDIM / 2)             // 256

__device__ __forceinline__ float gelu_exact(float x) {
    // jax.nn.gelu(approximate=False): x * 0.5 * (1 + erf(x / sqrt(2)))
    return 0.5f * x * (1.0f + erff(x * 0.70710678118654752440f));
}

__device__ __forceinline__ float softplus_f(float x) {
    // jax.nn.softplus = logaddexp(x, 0) = max(x,0) + log1p(exp(-|x|))
    return fmaxf(x, 0.0f) + log1pf(expf(-fabsf(x)));
}

// ---------------------------------------------------------------------------
// GEMM1: x1[m][n] = gelu( sum_k A[m][k] * W1[k][n] + b1[n] )
// A[m][k] = h[b][ idx[b][s][k/512] ][ k%512 ],  m = b*SWAPS + s  (gathered)
// Tile: BM=64, BN=64, BK=16; 256 threads, each computes 4x4.
// ---------------------------------------------------------------------------
__global__ __launch_bounds__(256) void gemm1_gather(
    const float* __restrict__ h, const int* __restrict__ idx,
    const float* __restrict__ W1, const float* __restrict__ b1,
    float* __restrict__ x1)
{
    __shared__ float sA[16][68];  // [k][m], padded (68*4=272B rows: 16B aligned, 2-way max)
    __shared__ float sB[16][68];  // [k][n]

    const int tid = threadIdx.x;
    const int tx = tid & 15, ty = tid >> 4;
    const int m0 = blockIdx.y * 64;
    const int n0 = blockIdx.x * 64;

    // A-load coords (fixed across K loop)
    const int ar = tid >> 2;            // row within tile: 0..63
    const int akc = (tid & 3) * 4;      // k offset within tile: 0,4,8,12
    const int am = m0 + ar;
    const int ab = am >> 12;            // / 4096
    const int as = am & 4095;
    const int* idx_row = idx + ((size_t)ab * SWAPS + as) * 4;
    const float* hb = h + (size_t)ab * NNODES * DDIM;

    // B-load coords
    const int bkr = tid >> 4;           // 0..15
    const int bnc = (tid & 15) * 4;     // 0..60

    float acc[4][4] = {};

    for (int kt = 0; kt < K1; kt += 16) {
        // ---- stage A tile (gathered) ----
        {
            const int seg = kt >> 9;                 // which of the 4 indices (16 | 512)
            const int node = idx_row[seg];
            const float* src = hb + (size_t)node * DDIM + (kt & 511) + akc;
            float4 v = *(const float4*)src;
            sA[akc + 0][ar] = v.x;
            sA[akc + 1][ar] = v.y;
            sA[akc + 2][ar] = v.z;
            sA[akc + 3][ar] = v.w;
        }
        // ---- stage B tile ----
        {
            float4 v = *(const float4*)(W1 + (size_t)(kt + bkr) * N1 + n0 + bnc);
            *(float4*)&sB[bkr][bnc] = v;
        }
        __syncthreads();

        #pragma unroll
        for (int k = 0; k < 16; ++k) {
            float4 a = *(const float4*)&sA[k][ty * 4];
            float4 b = *(const float4*)&sB[k][tx * 4];
            float av[4] = {a.x, a.y, a.z, a.w};
            float bv[4] = {b.x, b.y, b.z, b.w};
            #pragma unroll
            for (int i = 0; i < 4; ++i)
                #pragma unroll
                for (int j = 0; j < 4; ++j)
                    acc[i][j] = fmaf(av[i], bv[j], acc[i][j]);
        }
        __syncthreads();
    }

    // epilogue: +b1, gelu, store
    #pragma unroll
    for (int i = 0; i < 4; ++i) {
        const int m = m0 + ty * 4 + i;
        #pragma unroll
        for (int j = 0; j < 4; ++j) {
            const int n = n0 + tx * 4 + j;
            x1[(size_t)m * N1 + n] = gelu_exact(acc[i][j] + b1[n]);
        }
    }
}

// ---------------------------------------------------------------------------
// GEMM2: x2[m][n] = gelu( sum_k x1[m][k] * W2[k][n] + b2[n] )
// M=32768, K=512, N=256. Same tiling.
// ---------------------------------------------------------------------------
__global__ __launch_bounds__(256) void gemm2_dense(
    const float* __restrict__ x1, const float* __restrict__ W2,
    const float* __restrict__ b2, float* __restrict__ x2)
{
    __shared__ float sA[16][68];
    __shared__ float sB[16][68];

    const int tid = threadIdx.x;
    const int tx = tid & 15, ty = tid >> 4;
    const int m0 = blockIdx.y * 64;
    const int n0 = blockIdx.x * 64;

    const int ar = tid >> 2;
    const int akc = (tid & 3) * 4;
    const float* arow = x1 + (size_t)(m0 + ar) * K2;

    const int bkr = tid >> 4;
    const int bnc = (tid & 15) * 4;

    float acc[4][4] = {};

    for (int kt = 0; kt < K2; kt += 16) {
        {
            float4 v = *(const float4*)(arow + kt + akc);
            sA[akc + 0][ar] = v.x;
            sA[akc + 1][ar] = v.y;
            sA[akc + 2][ar] = v.z;
            sA[akc + 3][ar] = v.w;
        }
        {
            float4 v = *(const float4*)(W2 + (size_t)(kt + bkr) * N2 + n0 + bnc);
            *(float4*)&sB[bkr][bnc] = v;
        }
        __syncthreads();

        #pragma unroll
        for (int k = 0; k < 16; ++k) {
            float4 a = *(const float4*)&sA[k][ty * 4];
            float4 b = *(const float4*)&sB[k][tx * 4];
            float av[4] = {a.x, a.y, a.z, a.w};
            float bv[4] = {b.x, b.y, b.z, b.w};
            #pragma unroll
            for (int i = 0; i < 4; ++i)
                #pragma unroll
                for (int j = 0; j < 4; ++j)
                    acc[i][j] = fmaf(av[i], bv[j], acc[i][j]);
        }
        __syncthreads();
    }

    #pragma unroll
    for (int i = 0; i < 4; ++i) {
        const int m = m0 + ty * 4 + i;
        #pragma unroll
        for (int j = 0; j < 4; ++j) {
            const int n = n0 + tx * 4 + j;
            x2[(size_t)m * N2 + n] = gelu_exact(acc[i][j] + b2[n]);
        }
    }
}

// ---------------------------------------------------------------------------
// Head: out[m] = softplus( dot(x2[m], W3) + b3 ).  One wave per row.
// ---------------------------------------------------------------------------
__global__ __launch_bounds__(256) void head_kernel(
    const float* __restrict__ x2, const float* __restrict__ W3,
    const float* __restrict__ b3, float* __restrict__ out)
{
    const int wave = threadIdx.x >> 6;
    const int lane = threadIdx.x & 63;
    const int m = blockIdx.x * 4 + wave;
    if (m >= M_TOTAL) return;

    const float* row = x2 + (size_t)m * N2;
    float s = 0.0f;
    #pragma unroll
    for (int k = 0; k < N2; k += 64) s = fmaf(row[k + lane], W3[k + lane], s);

    #pragma unroll
    for (int off = 32; off > 0; off >>= 1) s += __shfl_down(s, off);

    if (lane == 0) {
        out[m] = softplus_f(s + b3[0]);
    }
}

// ---------------------------------------------------------------------------
extern "C" void kernel_launch(void* const* d_in, const int* in_sizes, int n_in,
                              void* d_out, int out_size, void* d_ws, size_t ws_size,
                              hipStream_t stream) {
    const float* h   = (const float*)d_in[0];
    const int*   idx = (const int*)d_in[1];   // int64 in ref but JAX x64 off -> int32
    const float* W1  = (const float*)d_in[2];
    const float* b1  = (const float*)d_in[3];
    const float* W2  = (const float*)d_in[4];
    const float* b2  = (const float*)d_in[5];
    const float* W3  = (const float*)d_in[6];
    const float* b3  = (const float*)d_in[7];
    float* out = (float*)d_out;

    // workspace: x1 (32768x512 f32 = 64MB), x2 (32768x256 f32 = 32MB)
    float* x1 = (float*)d_ws;
    float* x2 = x1 + (size_t)M_TOTAL * N1;

    gemm1_gather<<<dim3(N1 / 64, M_TOTAL / 64), 256, 0, stream>>>(h, idx, W1, b1, x1);
    gemm2_dense<<<dim3(N2 / 64, M_TOTAL / 64), 256, 0, stream>>>(x1, W2, b2, x2);
    head_kernel<<<dim3(M_TOTAL / 4), 256, 0, stream>>>(x2, W3, b3, out);
}

// Round 2
// 240.102 us; speedup vs baseline: 4.5309x; 4.5309x over previous
//
#include <hip/hip_runtime.h>
#include <math.h>

// Problem constants: B=8, N=2048, D=512, S=4096
#define BATCH 8
#define NNODES 2048
#define DDIM 512
#define SWAPS 4096
#define M_TOTAL (BATCH * SWAPS)   // 32768
#define K1 2048
#define N1 512
#define K2 512
#define N2 256

typedef __attribute__((ext_vector_type(8))) __bf16 bf16x8;   // MFMA A/B frag (4 VGPRs)
typedef __attribute__((ext_vector_type(4))) float f32x4;      // MFMA C/D frag

__device__ __forceinline__ float gelu_exact(float x) {
    return 0.5f * x * (1.0f + erff(x * 0.70710678118654752440f));
}
__device__ __forceinline__ float softplus_f(float x) {
    return fmaxf(x, 0.0f) + log1pf(expf(-fabsf(x)));
}
// fp32 -> bf16 RNE (bit-level, no hip_bf16 dependency)
__device__ __forceinline__ unsigned short f2bf(float f) {
    unsigned int u = __builtin_bit_cast(unsigned int, f);
    u += 0x7FFFu + ((u >> 16) & 1u);
    return (unsigned short)(u >> 16);
}
// async global->LDS, 16B per lane; lds base must be wave-uniform
__device__ __forceinline__ void glds16(const void* g, void* l) {
    __builtin_amdgcn_global_load_lds(
        (const __attribute__((address_space(1))) void*)g,
        (__attribute__((address_space(3))) void*)l, 16, 0, 0);
}

// ---------------------------------------------------------------------------
// convert: h (f32) -> h_bf (bf16);  W1[k][n] -> W1t[n][k] bf16;  W2 -> W2t bf16
// ---------------------------------------------------------------------------
__global__ __launch_bounds__(256) void convert_kernel(
    const float* __restrict__ h, const float* __restrict__ W1,
    const float* __restrict__ W2, unsigned short* __restrict__ h_bf,
    unsigned short* __restrict__ W1t, unsigned short* __restrict__ W2t)
{
    const int bid = blockIdx.x;
    if (bid < 8192) {                 // h: 8*2048*512 = 8388608 elems, 4/thread
        size_t i = ((size_t)bid * 256 + threadIdx.x) * 4;
        float4 v = *(const float4*)(h + i);
        ushort4 o = { f2bf(v.x), f2bf(v.y), f2bf(v.z), f2bf(v.w) };
        *(ushort4*)(h_bf + i) = o;
    } else if (bid < 8192 + 1024) {   // W1: 2048*512 elems, transpose
        size_t e = ((size_t)(bid - 8192) * 256 + threadIdx.x) * 4;
        int k = (int)(e >> 9), n = (int)(e & 511);
        float4 v = *(const float4*)(W1 + e);
        W1t[(size_t)(n + 0) * K1 + k] = f2bf(v.x);
        W1t[(size_t)(n + 1) * K1 + k] = f2bf(v.y);
        W1t[(size_t)(n + 2) * K1 + k] = f2bf(v.z);
        W1t[(size_t)(n + 3) * K1 + k] = f2bf(v.w);
    } else {                          // W2: 512*256 elems, transpose
        size_t e = ((size_t)(bid - 9216) * 256 + threadIdx.x) * 4;
        int k = (int)(e >> 8), n = (int)(e & 255);
        float4 v = *(const float4*)(W2 + e);
        W2t[(size_t)(n + 0) * K2 + k] = f2bf(v.x);
        W2t[(size_t)(n + 1) * K2 + k] = f2bf(v.y);
        W2t[(size_t)(n + 2) * K2 + k] = f2bf(v.z);
        W2t[(size_t)(n + 3) * K2 + k] = f2bf(v.w);
    }
}

// ---------------------------------------------------------------------------
// GEMM1 (gathered A): x1_bf[m][n] = bf16(gelu( A@W1 + b1 )), MFMA 16x16x32 bf16
// Block tile 128x128, BK=32, 4 waves (each 64x64 = 4x4 frags).
// A[m][k] = h_bf[b][idx[m][k/512]][k%512], m = b*4096+s.
// LDS: sA [128 rows][32 bf16] (64B rows), sB (W1t rows) same; staged via
// global_load_lds width=16 (per-lane gather addr, wave-uniform LDS base).
// ---------------------------------------------------------------------------
__global__ __launch_bounds__(256) void gemm1_mfma(
    const unsigned short* __restrict__ h_bf, const int* __restrict__ idx,
    const unsigned short* __restrict__ W1t, const float* __restrict__ b1,
    unsigned short* __restrict__ x1_bf)
{
    __shared__ __align__(16) char smem[16384];  // sA @0 (8KB), sB @8192 (8KB)

    const int tid = threadIdx.x;
    const int w = tid >> 6, lane = tid & 63;
    const int quad = lane >> 4, l16 = lane & 15;
    const int wr = w >> 1, wc = w & 1;
    const int m0 = blockIdx.y * 128, n0 = blockIdx.x * 128;

    // staging: chunk c = p*256 + tid covers sA/sB row c>>2, 16B piece c&3
    const int row0 = tid >> 2, sub = tid & 3;
    const int mA0 = m0 + row0, mA1 = m0 + row0 + 64;
    const int bb0 = mA0 >> 12, bb1 = mA1 >> 12;
    const int* ip0 = idx + (size_t)mA0 * 4;   // idx[(b*4096+s)*4] == idx[m*4]
    const int* ip1 = idx + (size_t)mA1 * 4;
    const unsigned short* bA0[4];
    const unsigned short* bA1[4];
    #pragma unroll
    for (int sg = 0; sg < 4; ++sg) {
        bA0[sg] = h_bf + ((size_t)bb0 * NNODES + ip0[sg]) * DDIM + sub * 8;
        bA1[sg] = h_bf + ((size_t)bb1 * NNODES + ip1[sg]) * DDIM + sub * 8;
    }
    const unsigned short* bB0 = W1t + (size_t)(n0 + row0) * K1 + sub * 8;
    const unsigned short* bB1 = W1t + (size_t)(n0 + row0 + 64) * K1 + sub * 8;

    // wave-uniform LDS staging bases
    char* ldsA0 = smem + w * 1024;
    char* ldsA1 = smem + 4096 + w * 1024;
    char* ldsB0 = smem + 8192 + w * 1024;
    char* ldsB1 = smem + 12288 + w * 1024;

    // fragment read pointers (ds_read_b128)
    const char* pa[4];
    const char* pb[4];
    #pragma unroll
    for (int i = 0; i < 4; ++i) {
        pa[i] = smem + (wr * 64 + i * 16 + l16) * 64 + quad * 16;
        pb[i] = smem + 8192 + (wc * 64 + i * 16 + l16) * 64 + quad * 16;
    }

    f32x4 acc[4][4] = {};

    auto kblock = [&](const unsigned short* a0, const unsigned short* a1,
                      const unsigned short* w0, const unsigned short* w1) {
        for (int kk = 0; kk < 16; ++kk) {
            glds16(a0 + kk * 32, ldsA0);
            glds16(a1 + kk * 32, ldsA1);
            glds16(w0 + kk * 32, ldsB0);
            glds16(w1 + kk * 32, ldsB1);
            __syncthreads();
            bf16x8 af[4], bfr[4];
            #pragma unroll
            for (int i = 0; i < 4; ++i) {
                af[i]  = *(const bf16x8*)pa[i];
                bfr[i] = *(const bf16x8*)pb[i];
            }
            #pragma unroll
            for (int i = 0; i < 4; ++i)
                #pragma unroll
                for (int j = 0; j < 4; ++j)
                    acc[i][j] = __builtin_amdgcn_mfma_f32_16x16x32_bf16(
                        af[i], bfr[j], acc[i][j], 0, 0, 0);
            __syncthreads();
        }
    };
    kblock(bA0[0], bA1[0], bB0,        bB1);
    kblock(bA0[1], bA1[1], bB0 + 512,  bB1 + 512);
    kblock(bA0[2], bA1[2], bB0 + 1024, bB1 + 1024);
    kblock(bA0[3], bA1[3], bB0 + 1536, bB1 + 1536);

    // epilogue: C/D layout col=lane&15, row=quad*4+reg
    #pragma unroll
    for (int j = 0; j < 4; ++j) {
        const int n = n0 + wc * 64 + j * 16 + l16;
        const float bias = b1[n];
        #pragma unroll
        for (int i = 0; i < 4; ++i) {
            f32x4 v = acc[i][j];
            #pragma unroll
            for (int r = 0; r < 4; ++r) {
                const int m = m0 + wr * 64 + i * 16 + quad * 4 + r;
                x1_bf[(size_t)m * N1 + n] = f2bf(gelu_exact(v[r] + bias));
            }
        }
    }
}

// ---------------------------------------------------------------------------
// GEMM2 (dense): x2[m][n] = gelu( x1 @ W2 + b2 ), fp32 out. M=32768,K=512,N=256
// ---------------------------------------------------------------------------
__global__ __launch_bounds__(256) void gemm2_mfma(
    const unsigned short* __restrict__ x1_bf, const unsigned short* __restrict__ W2t,
    const float* __restrict__ b2, float* __restrict__ x2)
{
    __shared__ __align__(16) char smem[16384];

    const int tid = threadIdx.x;
    const int w = tid >> 6, lane = tid & 63;
    const int quad = lane >> 4, l16 = lane & 15;
    const int wr = w >> 1, wc = w & 1;
    const int m0 = blockIdx.y * 128, n0 = blockIdx.x * 128;

    const int row0 = tid >> 2, sub = tid & 3;
    const unsigned short* bA0 = x1_bf + (size_t)(m0 + row0) * K2 + sub * 8;
    const unsigned short* bA1 = x1_bf + (size_t)(m0 + row0 + 64) * K2 + sub * 8;
    const unsigned short* bB0 = W2t + (size_t)(n0 + row0) * K2 + sub * 8;
    const unsigned short* bB1 = W2t + (size_t)(n0 + row0 + 64) * K2 + sub * 8;

    char* ldsA0 = smem + w * 1024;
    char* ldsA1 = smem + 4096 + w * 1024;
    char* ldsB0 = smem + 8192 + w * 1024;
    char* ldsB1 = smem + 12288 + w * 1024;

    const char* pa[4];
    const char* pb[4];
    #pragma unroll
    for (int i = 0; i < 4; ++i) {
        pa[i] = smem + (wr * 64 + i * 16 + l16) * 64 + quad * 16;
        pb[i] = smem + 8192 + (wc * 64 + i * 16 + l16) * 64 + quad * 16;
    }

    f32x4 acc[4][4] = {};

    for (int kk = 0; kk < 16; ++kk) {
        glds16(bA0 + kk * 32, ldsA0);
        glds16(bA1 + kk * 32, ldsA1);
        glds16(bB0 + kk * 32, ldsB0);
        glds16(bB1 + kk * 32, ldsB1);
        __syncthreads();
        bf16x8 af[4], bfr[4];
        #pragma unroll
        for (int i = 0; i < 4; ++i) {
            af[i]  = *(const bf16x8*)pa[i];
            bfr[i] = *(const bf16x8*)pb[i];
        }
        #pragma unroll
        for (int i = 0; i < 4; ++i)
            #pragma unroll
            for (int j = 0; j < 4; ++j)
                acc[i][j] = __builtin_amdgcn_mfma_f32_16x16x32_bf16(
                    af[i], bfr[j], acc[i][j], 0, 0, 0);
        __syncthreads();
    }

    #pragma unroll
    for (int j = 0; j < 4; ++j) {
        const int n = n0 + wc * 64 + j * 16 + l16;
        const float bias = b2[n];
        #pragma unroll
        for (int i = 0; i < 4; ++i) {
            f32x4 v = acc[i][j];
            #pragma unroll
            for (int r = 0; r < 4; ++r) {
                const int m = m0 + wr * 64 + i * 16 + quad * 4 + r;
                x2[(size_t)m * N2 + n] = gelu_exact(v[r] + bias);
            }
        }
    }
}

// ---------------------------------------------------------------------------
// Head: out[m] = softplus( dot(x2[m], W3) + b3 ). One wave per row.
// ---------------------------------------------------------------------------
__global__ __launch_bounds__(256) void head_kernel(
    const float* __restrict__ x2, const float* __restrict__ W3,
    const float* __restrict__ b3, float* __restrict__ out)
{
    const int wave = threadIdx.x >> 6;
    const int lane = threadIdx.x & 63;
    const int m = blockIdx.x * 4 + wave;
    if (m >= M_TOTAL) return;

    const float* row = x2 + (size_t)m * N2;
    float s = 0.0f;
    #pragma unroll
    for (int k = 0; k < N2; k += 64) s = fmaf(row[k + lane], W3[k + lane], s);
    #pragma unroll
    for (int off = 32; off > 0; off >>= 1) s += __shfl_down(s, off);
    if (lane == 0) out[m] = softplus_f(s + b3[0]);
}

// ---------------------------------------------------------------------------
extern "C" void kernel_launch(void* const* d_in, const int* in_sizes, int n_in,
                              void* d_out, int out_size, void* d_ws, size_t ws_size,
                              hipStream_t stream) {
    const float* h   = (const float*)d_in[0];
    const int*   idx = (const int*)d_in[1];
    const float* W1  = (const float*)d_in[2];
    const float* b1  = (const float*)d_in[3];
    const float* W2  = (const float*)d_in[4];
    const float* b2  = (const float*)d_in[5];
    const float* W3  = (const float*)d_in[6];
    const float* b3  = (const float*)d_in[7];
    float* out = (float*)d_out;

    // workspace layout (bytes):
    //   h_bf  @ 0        : 8*2048*512*2  = 16 MB
    //   W1t   @ 16 MB    : 512*2048*2    = 2 MB
    //   W2t   @ 18 MB    : 256*512*2     = 256 KB
    //   x1_bf @ 18.25 MB : 32768*512*2   = 32 MB
    //   x2    @ 50.25 MB : 32768*256*4   = 32 MB
    char* ws = (char*)d_ws;
    unsigned short* h_bf  = (unsigned short*)ws;
    unsigned short* W1t   = (unsigned short*)(ws + (16u << 20));
    unsigned short* W2t   = (unsigned short*)(ws + (18u << 20));
    unsigned short* x1_bf = (unsigned short*)(ws + (18u << 20) + (256u << 10));
    float*          x2    = (float*)(ws + (50u << 20) + (256u << 10));

    convert_kernel<<<9344, 256, 0, stream>>>(h, W1, W2, h_bf, W1t, W2t);
    gemm1_mfma<<<dim3(N1 / 128, M_TOTAL / 128), 256, 0, stream>>>(h_bf, idx, W1t, b1, x1_bf);
    gemm2_mfma<<<dim3(N2 / 128, M_TOTAL / 128), 256, 0, stream>>>(x1_bf, W2t, b2, x2);
    head_kernel<<<M_TOTAL / 4, 256, 0, stream>>>(x2, W3, b3, out);
}